// Round 8
// baseline (12760.448 us; speedup 1.0000x reference)
//
#include <hip/hip_runtime.h>
#include <hip/hip_bf16.h>

#define NPTS 16384
#define MCENT 4096
#define BCLD 2
#define FDIM 32
#define H1DIM 64
#define CODIM 128
#define KNBR 64
// largest fp32 <= 0.04 (float64) == fp32(0.04f) == 0.039999999105930328
#define R2CUT 0.04f

// Exact (numpy-order, contraction-free) squared distance: ((dx*dx+dy*dy)+dz*dz)
__device__ __forceinline__ float d2e(float ax, float ay, float az,
                                     float bx, float by, float bz) {
  float dx = __fsub_rn(ax, bx);
  float dy = __fsub_rn(ay, by);
  float dz = __fsub_rn(az, bz);
  return __fadd_rn(__fadd_rn(__fmul_rn(dx, dx), __fmul_rn(dy, dy)), __fmul_rn(dz, dz));
}

// 3-bit spread for 9-bit Morton: b2 b1 b0 -> b2 _ _ b1 _ _ b0 (bits 6,3,0)
__device__ __forceinline__ int spread3(int v) {
  return ((v & 4) << 4) | ((v & 2) << 2) | (v & 1);
}
__device__ __forceinline__ int cell_of(float x, float y, float z) {
  int cx = min(7, (int)(x * 8.0f));
  int cy = min(7, (int)(y * 8.0f));
  int cz = min(7, (int)(z * 8.0f));
  // Morton order: a spatial ball maps to few contiguous cell ranges
  return (spread3(cx) << 2) | (spread3(cy) << 1) | spread3(cz);
}

// Lexicographic max over (bits, nidx) pairs via DPP (VALU pipe — no LDS).
// Identity (0,0) can never beat a real candidate (real nidx = ~oidx > 0).
#define DPP_LEXMAX_STEP(bb, nn, ctrl)                                          \
  do {                                                                         \
    unsigned _ob = (unsigned)__builtin_amdgcn_update_dpp(0, (int)(bb), ctrl,   \
                                                         0xf, 0xf, false);     \
    unsigned _on = (unsigned)__builtin_amdgcn_update_dpp(0, (int)(nn), ctrl,   \
                                                         0xf, 0xf, false);     \
    bool _t = (_ob > (bb)) || (_ob == (bb) && _on > (nn));                     \
    (bb) = _t ? _ob : (bb);                                                    \
    (nn) = _t ? _on : (nn);                                                    \
  } while (0)

__device__ __forceinline__ int rdlane(int v, int l) {
  return __builtin_amdgcn_readlane(v, l);
}
__device__ __forceinline__ float rdlanef(float v, int l) {
  return __int_as_float(__builtin_amdgcn_readlane(__float_as_int(v), l));
}

// AGPR pinning: gfx950 unified VGPR/AGPR file; no MFMA here so AGPRs are free.
// "a"-constraint forces allocation — the allocator CANNOT spill these.
__device__ __forceinline__ void ag_write_f(float& slot, float v) {
  asm volatile("v_accvgpr_write_b32 %0, %1" : "=a"(slot) : "v"(v));
}
__device__ __forceinline__ float ag_read_f(const float& slot) {
  float r;
  asm volatile("v_accvgpr_read_b32 %0, %1" : "=v"(r) : "a"(slot));
  return r;
}
__device__ __forceinline__ void ag_write_u(unsigned& slot, unsigned v) {
  asm volatile("v_accvgpr_write_b32 %0, %1" : "=a"(slot) : "v"(v));
}
__device__ __forceinline__ unsigned ag_read_u(const unsigned& slot) {
  unsigned r;
  asm volatile("v_accvgpr_read_b32 %0, %1" : "=v"(r) : "a"(slot));
  return r;
}

// ---------------- Kernel 1: farthest point sampling (1 block per cloud) ----
// 512 threads x 32 pts (two 16-pt halves, per-half bbox + cached best),
// Morton-counting-sorted so a dirty ball maps to few contiguous thread
// ranges. DPP lexmax reductions; parity-double-buffered LDS slots; ONE
// barrier/iter; winners buffered in LDS, dumped once at the end.
//
// R0-R7 ledger: (1) dirty-path data source is ~cost-neutral across scratch/
// LDS/L2/AGPR at 16 waves — NOT the dominant term; (2) the dominant term is
// per-SIMD issue of the redundant fixed path (16 waves x ~80 instr x 2cy) +
// barrier width; (3) 512-thread attempts failed ONLY via broken data paths
// (spill at 128-reg cap in R1, serialized L2 reloads in R2). This version
// combines 8 waves (halves redundant issue + barrier width; cross-wave
// reduce 8 slots / 3 DPP steps) with an unspillable AGPR data path:
// px/py/pz/~idx[32] pinned in 128 AGPRs, d[32]+~60 scalars ~95 VGPRs under
// the waves_per_eu(2,2) 256-reg unified budget. Dirty path is pure VALU.
__global__ __attribute__((amdgpu_flat_work_group_size(512, 512),
                          amdgpu_waves_per_eu(2, 2)))
void fps_kernel(const float* __restrict__ pos,
                int* __restrict__ fps_idx,
                float4* __restrict__ ws_sorted) {
  const int b = blockIdx.x;
  const float* P = pos + (size_t)b * NPTS * 3;
  float4* S = ws_sorted + (size_t)b * NPTS;
  const int tid = threadIdx.x;
  const int lane = tid & 63;
  const int wave = tid >> 6;  // 0..7

  __shared__ int hist[512];
  __shared__ int offs[512];
  __shared__ unsigned long long skey[2][8];
  __shared__ float4 spos[2][8];
  __shared__ int winners[MCENT];

  // ---- phase A: counting sort by Morton cell into ws_sorted (global) ----
  hist[tid] = 0;
  __syncthreads();
#pragma unroll 4
  for (int j = 0; j < 32; ++j) {
    int i = tid + j * 512;
    float x = P[3 * i + 0], y = P[3 * i + 1], z = P[3 * i + 2];
    atomicAdd(&hist[cell_of(x, y, z)], 1);
  }
  __syncthreads();
  if (tid < 64) {  // wave 0: exclusive scan of 512 cells
    int base = tid * 8;
    int loc[8];
    int run = 0;
#pragma unroll
    for (int k = 0; k < 8; ++k) { loc[k] = run; run += hist[base + k]; }
    int inc = run;
#pragma unroll
    for (int off = 1; off < 64; off <<= 1) {
      int o = __shfl_up(inc, off);
      if (tid >= off) inc += o;
    }
    int ex = inc - run;
#pragma unroll
    for (int k = 0; k < 8; ++k) offs[base + k] = ex + loc[k];
  }
  __syncthreads();
#pragma unroll 4
  for (int j = 0; j < 32; ++j) {
    int i = tid + j * 512;
    float x = P[3 * i + 0], y = P[3 * i + 1], z = P[3 * i + 2];
    int p = atomicAdd(&offs[cell_of(x, y, z)], 1);
    S[p] = make_float4(x, y, z, __int_as_float(i));
  }
  __syncthreads();  // global S writes drained before re-read (validated in R2)

  // ---- phase B: load 32 pts into AGPRs, init d, per-half bbox + best ----
  float apx[32], apy[32], apz[32];  // AGPR-pinned positions (96 AGPRs)
  unsigned apn[32];                 // AGPR-pinned ~original_index (32 AGPRs)
  float d[32];
  float bxm[2], bxM[2], bym[2], byM[2], bzm[2], bzM[2];
  unsigned hb[2], hn[2];            // per-half best (d bits, ~oidx)
  float hx[2], hy[2], hz[2];        // per-half best position
  const float x0 = P[0], y0 = P[1], z0 = P[2];
#pragma unroll
  for (int h = 0; h < 2; ++h) {
    unsigned nb = 0u, nn2 = 0u;
    float nx = 0.f, ny = 0.f, nz = 0.f;
#pragma unroll
    for (int jj = 0; jj < 16; ++jj) {
      const int j = h * 16 + jj;
      float4 v = S[tid * 32 + j];
      ag_write_f(apx[j], v.x);
      ag_write_f(apy[j], v.y);
      ag_write_f(apz[j], v.z);
      unsigned nj = ~(unsigned)__float_as_int(v.w);
      ag_write_u(apn[j], nj);
      float dj = d2e(v.x, v.y, v.z, x0, y0, z0);
      d[j] = dj;
      if (jj == 0) {
        bxm[h] = v.x; bxM[h] = v.x; bym[h] = v.y; byM[h] = v.y;
        bzm[h] = v.z; bzM[h] = v.z;
      } else {
        bxm[h] = fminf(bxm[h], v.x); bxM[h] = fmaxf(bxM[h], v.x);
        bym[h] = fminf(bym[h], v.y); byM[h] = fmaxf(byM[h], v.y);
        bzm[h] = fminf(bzm[h], v.z); bzM[h] = fmaxf(bzM[h], v.z);
      }
      unsigned db = __float_as_uint(dj);
      bool t = (db > nb) || (db == nb && nj > nn2);
      nb = t ? db : nb; nn2 = t ? nj : nn2;
      nx = t ? v.x : nx; ny = t ? v.y : ny; nz = t ? v.z : nz;
    }
    hb[h] = nb; hn[h] = nn2; hx[h] = nx; hy[h] = ny; hz[h] = nz;
  }

  if (tid == 0) winners[0] = 0;

  bool wavedirty = true;
  unsigned cwb = 0u, cwn = 0u;           // cached wave-winner key
  float cwx = 0.f, cwy = 0.f, cwz = 0.f; // cached wave-winner pos

  for (int m = 1; m < MCENT; ++m) {
    const int par = m & 1;

    if (wavedirty) {  // merged thread best, then full-wave DPP lexmax
      unsigned tb = hb[0], tn = hn[0];
      float tx = hx[0], ty = hy[0], tz = hz[0];
      {
        bool t = (hb[1] > tb) || (hb[1] == tb && hn[1] > tn);
        tb = t ? hb[1] : tb; tn = t ? hn[1] : tn;
        tx = t ? hx[1] : tx; ty = t ? hy[1] : ty; tz = t ? hz[1] : tz;
      }
      unsigned bb = tb, nn = tn;
      DPP_LEXMAX_STEP(bb, nn, 0x111);  // row_shr:1
      DPP_LEXMAX_STEP(bb, nn, 0x112);  // row_shr:2
      DPP_LEXMAX_STEP(bb, nn, 0x114);  // row_shr:4
      DPP_LEXMAX_STEP(bb, nn, 0x118);  // row_shr:8
      DPP_LEXMAX_STEP(bb, nn, 0x142);  // row_bcast:15
      DPP_LEXMAX_STEP(bb, nn, 0x143);  // row_bcast:31
      cwb = (unsigned)rdlane((int)bb, 63);
      cwn = (unsigned)rdlane((int)nn, 63);
      unsigned long long own = __ballot(tb == cwb && tn == cwn);
      int ol = (int)__ffsll(own) - 1;  // unique: nidx carries a unique point id
      cwx = rdlanef(tx, ol);
      cwy = rdlanef(ty, ol);
      cwz = rdlanef(tz, ol);
    }
    if (lane == 0) {  // always republish (parity buffer alternates)
      skey[par][wave] = ((unsigned long long)cwb << 32) | (unsigned long long)cwn;
      spos[par][wave] = make_float4(cwx, cwy, cwz, 0.0f);
    }
    __syncthreads();  // only lgkm traffic pending — cheap drain

    // cross-wave reduce: lanes 0..7 each take one slot, 3-step DPP lexmax
    unsigned rb, rn;
    unsigned sb0 = 0u, sn0 = 0u;
    {
      unsigned bb = 0u, nn = 0u;
      if (lane < 8) {
        unsigned long long kk = skey[par][lane];
        bb = (unsigned)(kk >> 32);
        nn = (unsigned)kk;
        sb0 = bb; sn0 = nn;
        DPP_LEXMAX_STEP(bb, nn, 0x111);
        DPP_LEXMAX_STEP(bb, nn, 0x112);
        DPP_LEXMAX_STEP(bb, nn, 0x114);
      }
      rb = (unsigned)rdlane((int)bb, 7);
      rn = (unsigned)rdlane((int)nn, 7);
    }
    unsigned long long wm = __ballot(lane < 8 && sb0 == rb && sn0 == rn);
    int ws = (int)__ffsll(wm) - 1;   // winning slot (wave) id — unique key
    float4 wp = spos[par][ws];       // single b128 broadcast read
    if (tid == 0) winners[m] = (int)(~rn);

    // per-half prune: lower-bound distance from winner to half bbox
    bool mydirty = false;
#pragma unroll
    for (int h = 0; h < 2; ++h) {
      float ex = fmaxf(fmaxf(bxm[h] - wp.x, wp.x - bxM[h]), 0.0f);
      float ey = fmaxf(fmaxf(bym[h] - wp.y, wp.y - byM[h]), 0.0f);
      float ez = fmaxf(fmaxf(bzm[h] - wp.z, wp.z - bzM[h]), 0.0f);
      float lb = (ex * ex + ey * ey + ez * ez) * 0.999f;
      if (lb < __uint_as_float(hb[h])) {
        mydirty = true;
        unsigned nb = 0u, nn2 = 0u;
        float nx = 0.f, ny = 0.f, nz = 0.f;
#pragma unroll
        for (int jj = 0; jj < 16; ++jj) {
          const int j = h * 16 + jj;
          float qx = ag_read_f(apx[j]);
          float qy = ag_read_f(apy[j]);
          float qz = ag_read_f(apz[j]);
          unsigned nj = ag_read_u(apn[j]);
          float dj = fminf(d[j], d2e(qx, qy, qz, wp.x, wp.y, wp.z));
          d[j] = dj;
          unsigned db = __float_as_uint(dj);
          bool t = (db > nb) || (db == nb && nj > nn2);
          nb = t ? db : nb; nn2 = t ? nj : nn2;
          nx = t ? qx : nx; ny = t ? qy : ny; nz = t ? qz : nz;
        }
        hb[h] = nb; hn[h] = nn2; hx[h] = nx; hy[h] = ny; hz[h] = nz;
      }
    }
    wavedirty = (__ballot(mydirty) != 0ULL);
  }

  __syncthreads();
  for (int i = tid; i < MCENT; i += 512) fps_idx[b * MCENT + i] = winners[i];
}

// ------------- Kernel 2: ball query + K-smallest selection (1 wave/centroid) --
__global__ __launch_bounds__(256) void ballq_kernel(const float* __restrict__ pos,
                                                    const int* __restrict__ fps_idx,
                                                    int* __restrict__ nbr,
                                                    float* __restrict__ out_pc,
                                                    float* __restrict__ out_batch) {
  const int wave = threadIdx.x >> 6;
  const int lane = threadIdx.x & 63;
  const int c = blockIdx.x * 4 + wave;   // global centroid id
  const int b = c >> 12;                 // 4096 centroids per cloud
  const float* P = pos + (size_t)b * NPTS * 3;

  const int ci = fps_idx[c];
  const float cx = P[3 * ci + 0];
  const float cy = P[3 * ci + 1];
  const float cz = P[3 * ci + 2];
  if (lane == 0) {
    out_pc[3 * c + 0] = cx;
    out_pc[3 * c + 1] = cy;
    out_pc[3 * c + 2] = cz;
    out_batch[c] = (float)b;
  }

  __shared__ unsigned long long list[4][1024];
  __shared__ int cnt[4];
  if (lane == 0) cnt[wave] = 0;

  for (int i = lane; i < NPTS; i += 64) {
    const float qx = P[3 * i + 0];
    const float qy = P[3 * i + 1];
    const float qz = P[3 * i + 2];
    const float dd = d2e(cx, cy, cz, qx, qy, qz);
    if (dd <= R2CUT) {
      int p = atomicAdd(&cnt[wave], 1);
      if (p < 1024)
        list[wave][p] = ((unsigned long long)__float_as_uint(dd) << 32)
                      | (unsigned long long)(unsigned)i;
    }
  }
  __syncthreads();

  int n = cnt[wave];
  if (n > 1024) n = 1024;

  unsigned long long loc[16];
#pragma unroll
  for (int k = 0; k < 16; ++k) {
    int i = lane + k * 64;
    loc[k] = (i < n) ? list[wave][i] : ~0ULL;
  }
  unsigned long long mv = loc[0];
#pragma unroll
  for (int k = 1; k < 16; ++k)
    if (loc[k] < mv) mv = loc[k];

  int myout = -1;
  for (int s = 0; s < 64; ++s) {
    unsigned long long wmin = mv;
#pragma unroll
    for (int off = 32; off >= 1; off >>= 1) {
      unsigned long long o = __shfl_xor(wmin, off);
      if (o < wmin) wmin = o;
    }
    if (lane == s) myout = (wmin == ~0ULL) ? -1 : (int)(unsigned)wmin;
    if (mv == wmin && wmin != ~0ULL) {
#pragma unroll
      for (int k = 0; k < 16; ++k)
        if (loc[k] == wmin) loc[k] = ~0ULL;
      mv = loc[0];
#pragma unroll
      for (int k = 1; k < 16; ++k)
        if (loc[k] < mv) mv = loc[k];
    }
  }
  nbr[c * KNBR + lane] = myout;
}

// ------------- Kernel 3: MLP (35->64 relu ->128) + masked max-pool ----------
__global__ __launch_bounds__(256) void mlp_kernel(const float* __restrict__ pos,
                                                  const float* __restrict__ x,
                                                  const int* __restrict__ fps_idx,
                                                  const int* __restrict__ nbr,
                                                  const float* __restrict__ W1,
                                                  const float* __restrict__ b1,
                                                  const float* __restrict__ W2,
                                                  const float* __restrict__ b2,
                                                  float* __restrict__ out) {
  const int c = blockIdx.x;
  const int b = c >> 12;
  const float* P = pos + (size_t)b * NPTS * 3;
  const float* X = x + (size_t)b * NPTS * FDIM;

  __shared__ float W1s[35 * 64];
  __shared__ float W2s[64 * 128];
  __shared__ float b1s[64];
  __shared__ float b2s[128];
  __shared__ float h1s[64][64];
  __shared__ float pmax[2][128];
  __shared__ int validk[64];

  const int tid = threadIdx.x;
  for (int i = tid; i < 35 * 64; i += 256) W1s[i] = W1[i];
  for (int i = tid; i < 64 * 128; i += 256) W2s[i] = W2[i];
  if (tid < 64) b1s[tid] = b1[tid];
  else if (tid < 192) b2s[tid - 64] = b2[tid - 64];

  const int ci = fps_idx[c];
  const float c5x = P[3 * ci + 0] / 0.2f;  // faithful: pos_i / r
  const float c5y = P[3 * ci + 1] / 0.2f;
  const float c5z = P[3 * ci + 2] / 0.2f;

  const int k = tid >> 2, q = tid & 3;
  const int nk = nbr[c * KNBR + k];
  if (q == 0) validk[k] = (nk >= 0) ? 1 : 0;
  const int nkc = (nk < 0) ? 0 : nk;

  float msg[35];
  const float4* Xr = (const float4*)(X + (size_t)nkc * FDIM);
#pragma unroll
  for (int i4 = 0; i4 < 8; ++i4) {
    float4 v = Xr[i4];
    msg[i4 * 4 + 0] = v.x; msg[i4 * 4 + 1] = v.y;
    msg[i4 * 4 + 2] = v.z; msg[i4 * 4 + 3] = v.w;
  }
  msg[32] = P[3 * nkc + 0] - c5x;
  msg[33] = P[3 * nkc + 1] - c5y;
  msg[34] = P[3 * nkc + 2] - c5z;

  __syncthreads();

  float acc[16];
#pragma unroll
  for (int h = 0; h < 16; ++h) acc[h] = b1s[q * 16 + h];
#pragma unroll
  for (int i = 0; i < 35; ++i) {
    const float m = msg[i];
    const float4* wrow = (const float4*)&W1s[i * 64 + q * 16];
#pragma unroll
    for (int j4 = 0; j4 < 4; ++j4) {
      float4 w = wrow[j4];
      acc[j4 * 4 + 0] += m * w.x;
      acc[j4 * 4 + 1] += m * w.y;
      acc[j4 * 4 + 2] += m * w.z;
      acc[j4 * 4 + 3] += m * w.w;
    }
  }
#pragma unroll
  for (int h = 0; h < 16; ++h) h1s[k][q * 16 + h] = fmaxf(acc[h], 0.0f);
  __syncthreads();

  const int ch = tid & 127, half = tid >> 7;
  float w2r[64];
#pragma unroll
  for (int i = 0; i < 64; ++i) w2r[i] = W2s[i * 128 + ch];

  float mx = -INFINITY;
  for (int k2 = half * 32; k2 < half * 32 + 32; ++k2) {
    if (!validk[k2]) continue;
    float s = b2s[ch];
    const float4* hr = (const float4*)h1s[k2];
#pragma unroll
    for (int i4 = 0; i4 < 16; ++i4) {
      float4 h4 = hr[i4];
      s += h4.x * w2r[i4 * 4 + 0] + h4.y * w2r[i4 * 4 + 1]
         + h4.z * w2r[i4 * 4 + 2] + h4.w * w2r[i4 * 4 + 3];
    }
    mx = fmaxf(mx, s);
  }
  pmax[half][ch] = mx;
  __syncthreads();

  if (tid < 128) {
    float m2 = fmaxf(pmax[0][tid], pmax[1][tid]);
    out[(size_t)c * CODIM + tid] = (m2 > -INFINITY) ? m2 : 0.0f;
  }
}

extern "C" void kernel_launch(void* const* d_in, const int* in_sizes, int n_in,
                              void* d_out, int out_size, void* d_ws, size_t ws_size,
                              hipStream_t stream) {
  const float* x   = (const float*)d_in[0];
  const float* pos = (const float*)d_in[1];
  const float* W1  = (const float*)d_in[3];
  const float* b1  = (const float*)d_in[4];
  const float* W2  = (const float*)d_in[5];
  const float* b2  = (const float*)d_in[6];
  float* out = (float*)d_out;

  int* fps_idx = (int*)d_ws;                  // B*M ints = 32 KiB
  int* nbr     = (int*)d_ws + BCLD * MCENT;   // B*M*K ints = 2 MiB
  // fps scratch aliases the nbr region (fps completes before ballq writes nbr)
  float4* ws_sorted = (float4*)nbr;           // B*N float4 = 512 KiB

  float* out_pc    = out + (size_t)BCLD * MCENT * CODIM;
  float* out_batch = out_pc + (size_t)BCLD * MCENT * 3;

  hipLaunchKernelGGL(fps_kernel, dim3(BCLD), dim3(512), 0, stream, pos, fps_idx, ws_sorted);
  hipLaunchKernelGGL(ballq_kernel, dim3(BCLD * MCENT / 4), dim3(256), 0, stream,
                     pos, fps_idx, nbr, out_pc, out_batch);
  hipLaunchKernelGGL(mlp_kernel, dim3(BCLD * MCENT), dim3(256), 0, stream,
                     pos, x, fps_idx, nbr, W1, b1, W2, b2, out);
}

// Round 9
// 7691.982 us; speedup vs baseline: 1.6589x; 1.6589x over previous
//
#include <hip/hip_runtime.h>
#include <hip/hip_bf16.h>

#define NPTS 16384
#define MCENT 4096
#define BCLD 2
#define FDIM 32
#define H1DIM 64
#define CODIM 128
#define KNBR 64
// largest fp32 <= 0.04 (float64) == fp32(0.04f) == 0.039999999105930328
#define R2CUT 0.04f

// Exact (numpy-order, contraction-free) squared distance: ((dx*dx+dy*dy)+dz*dz)
__device__ __forceinline__ float d2e(float ax, float ay, float az,
                                     float bx, float by, float bz) {
  float dx = __fsub_rn(ax, bx);
  float dy = __fsub_rn(ay, by);
  float dz = __fsub_rn(az, bz);
  return __fadd_rn(__fadd_rn(__fmul_rn(dx, dx), __fmul_rn(dy, dy)), __fmul_rn(dz, dz));
}

// 3-bit spread for 9-bit Morton: b2 b1 b0 -> b2 _ _ b1 _ _ b0 (bits 6,3,0)
__device__ __forceinline__ int spread3(int v) {
  return ((v & 4) << 4) | ((v & 2) << 2) | (v & 1);
}
__device__ __forceinline__ int cell_of(float x, float y, float z) {
  int cx = min(7, (int)(x * 8.0f));
  int cy = min(7, (int)(y * 8.0f));
  int cz = min(7, (int)(z * 8.0f));
  // Morton order: a spatial ball maps to few contiguous cell ranges
  return (spread3(cx) << 2) | (spread3(cy) << 1) | spread3(cz);
}

// Lexicographic max over (bits, nidx) pairs via DPP (VALU pipe — no LDS).
// Identity (0,0) can never beat a real candidate (real nidx = ~oidx > 0).
#define DPP_LEXMAX_STEP(bb, nn, ctrl)                                          \
  do {                                                                         \
    unsigned _ob = (unsigned)__builtin_amdgcn_update_dpp(0, (int)(bb), ctrl,   \
                                                         0xf, 0xf, false);     \
    unsigned _on = (unsigned)__builtin_amdgcn_update_dpp(0, (int)(nn), ctrl,   \
                                                         0xf, 0xf, false);     \
    bool _t = (_ob > (bb)) || (_ob == (bb) && _on > (nn));                     \
    (bb) = _t ? _ob : (bb);                                                    \
    (nn) = _t ? _on : (nn);                                                    \
  } while (0)

__device__ __forceinline__ int rdlane(int v, int l) {
  return __builtin_amdgcn_readlane(v, l);
}
__device__ __forceinline__ float rdlanef(float v, int l) {
  return __int_as_float(__builtin_amdgcn_readlane(__float_as_int(v), l));
}

// ---------------- Kernel 1: farthest point sampling (1 block per cloud) ----
// 1024 threads x 16 pts, counting-sorted by MORTON cell id (8x8x8) so a dirty
// ball maps to few contiguous thread ranges (few dirty waves). Per-chunk bbox
// prune (0.999 margin >> fp rounding) skips provably-unchanged chunks. DPP
// lexmax reductions; 16 parity-double-buffered LDS slots (key b64 + pos b128);
// ONE barrier/iter; winners buffered in LDS, dumped once at the end.
//
// SESSION LEDGER (R0-R8, all harness-measured) — why this exact form:
//  * This structure @ 64 VGPR (compiler-chosen spill of the point arrays) is
//    the empirical optimum: steady fps ~6.9 ms, total ~7.69 ms (R0, R3).
//  * Data-path variants, same geometry: AGPR-pinned pos 7.3 ms (R7); d-in-LDS
//    8.8 ms (R6); explicit L2 reload 13.5 ms (R2); cross-barrier inline-asm
//    prefetch 28 ms (R5 — floods L2 unconditionally).
//  * 8-wave geometry (512 thr x 32 pts) loses with EVERY data path: 11.4 ms
//    (R1 spill), 13.5 ms (R2 L2), 12.6 ms (R8 AGPR) — longer per-thread dirty
//    chain on the barrier-convoy critical path + less latency hiding.
//  * Occupancy knobs are no-ops or harmful here: __launch_bounds__(1024,1)
//    identical (R3); amdgpu_waves_per_eu(4,4) identical +SGPR only (R4).
//  * Residual cost is the serial 4095-iteration sync/reduce/straggler chain
//    on one CU (~4030 cy/iter) — a latency floor, not a counter-visible
//    memory/compute roofline; no tested lever moves it.
__global__ __launch_bounds__(1024) void fps_kernel(const float* __restrict__ pos,
                                                   int* __restrict__ fps_idx,
                                                   float4* __restrict__ ws_sorted) {
  const int b = blockIdx.x;
  const float* P = pos + (size_t)b * NPTS * 3;
  float4* S = ws_sorted + (size_t)b * NPTS;
  const int tid = threadIdx.x;
  const int lane = tid & 63;
  const int wave = tid >> 6;  // 0..15

  __shared__ int hist[512];
  __shared__ int offs[512];
  __shared__ unsigned long long skey[2][16];
  __shared__ float4 spos[2][16];
  __shared__ int winners[MCENT];

  // ---- phase A: counting sort by Morton cell into ws_sorted (global) ----
  if (tid < 512) hist[tid] = 0;
  __syncthreads();
#pragma unroll 4
  for (int j = 0; j < 16; ++j) {
    int i = tid + j * 1024;
    float x = P[3 * i + 0], y = P[3 * i + 1], z = P[3 * i + 2];
    atomicAdd(&hist[cell_of(x, y, z)], 1);
  }
  __syncthreads();
  if (tid < 64) {  // wave 0: exclusive scan of 512 cells
    int base = tid * 8;
    int loc[8];
    int run = 0;
#pragma unroll
    for (int k = 0; k < 8; ++k) { loc[k] = run; run += hist[base + k]; }
    int inc = run;
#pragma unroll
    for (int off = 1; off < 64; off <<= 1) {
      int o = __shfl_up(inc, off);
      if (tid >= off) inc += o;
    }
    int ex = inc - run;
#pragma unroll
    for (int k = 0; k < 8; ++k) offs[base + k] = ex + loc[k];
  }
  __syncthreads();
#pragma unroll 4
  for (int j = 0; j < 16; ++j) {
    int i = tid + j * 1024;
    float x = P[3 * i + 0], y = P[3 * i + 1], z = P[3 * i + 2];
    int p = atomicAdd(&offs[cell_of(x, y, z)], 1);
    S[p] = make_float4(x, y, z, __int_as_float(i));
  }
  __syncthreads();  // global S writes drained before re-read (validated in R2)

  // ---- phase B: load 16-pt chunk, init d vs original point 0, bbox, best ----
  float px[16], py[16], pz[16], d[16];
  unsigned nidx[16];  // ~original_index (tiebreak payload, precomputed)
  const float x0 = P[0], y0 = P[1], z0 = P[2];
  float bxm, bxM, bym, byM, bzm, bzM;
  unsigned tb = 0u, tn = 0u;           // thread-best (d bits, ~oidx)
  float tx = 0.f, ty = 0.f, tz = 0.f;  // thread-best position
#pragma unroll
  for (int j = 0; j < 16; ++j) {
    float4 v = S[tid * 16 + j];
    px[j] = v.x; py[j] = v.y; pz[j] = v.z;
    nidx[j] = ~(unsigned)__float_as_int(v.w);
    float dj = d2e(v.x, v.y, v.z, x0, y0, z0);
    d[j] = dj;
    if (j == 0) {
      bxm = v.x; bxM = v.x; bym = v.y; byM = v.y; bzm = v.z; bzM = v.z;
    } else {
      bxm = fminf(bxm, v.x); bxM = fmaxf(bxM, v.x);
      bym = fminf(bym, v.y); byM = fmaxf(byM, v.y);
      bzm = fminf(bzm, v.z); bzM = fmaxf(bzM, v.z);
    }
    unsigned db = __float_as_uint(dj);
    unsigned nj = nidx[j];
    bool t = (db > tb) || (db == tb && nj > tn);
    tb = t ? db : tb; tn = t ? nj : tn;
    tx = t ? v.x : tx; ty = t ? v.y : ty; tz = t ? v.z : tz;
  }

  if (tid == 0) winners[0] = 0;

  bool wavedirty = true;
  unsigned cwb = 0u, cwn = 0u;           // cached wave-winner key
  float cwx = 0.f, cwy = 0.f, cwz = 0.f; // cached wave-winner pos

  for (int m = 1; m < MCENT; ++m) {
    const int par = m & 1;

    if (wavedirty) {  // recompute wave winner via full-wave DPP lexmax
      unsigned bb = tb, nn = tn;
      DPP_LEXMAX_STEP(bb, nn, 0x111);  // row_shr:1
      DPP_LEXMAX_STEP(bb, nn, 0x112);  // row_shr:2
      DPP_LEXMAX_STEP(bb, nn, 0x114);  // row_shr:4
      DPP_LEXMAX_STEP(bb, nn, 0x118);  // row_shr:8
      DPP_LEXMAX_STEP(bb, nn, 0x142);  // row_bcast:15
      DPP_LEXMAX_STEP(bb, nn, 0x143);  // row_bcast:31
      cwb = (unsigned)rdlane((int)bb, 63);
      cwn = (unsigned)rdlane((int)nn, 63);
      unsigned long long own = __ballot(tb == cwb && tn == cwn);
      int ol = (int)__ffsll(own) - 1;  // unique: nidx carries a unique point id
      cwx = rdlanef(tx, ol);
      cwy = rdlanef(ty, ol);
      cwz = rdlanef(tz, ol);
    }
    if (lane == 0) {  // always republish (parity buffer alternates)
      skey[par][wave] = ((unsigned long long)cwb << 32) | (unsigned long long)cwn;
      spos[par][wave] = make_float4(cwx, cwy, cwz, 0.0f);
    }
    __syncthreads();  // only lgkm traffic pending — cheap drain

    // cross-wave reduce: lanes 0..15 each take one slot, 4-step DPP lexmax
    unsigned rb, rn;
    unsigned sb0 = 0u, sn0 = 0u;
    {
      unsigned bb = 0u, nn = 0u;
      if (lane < 16) {
        unsigned long long kk = skey[par][lane];
        bb = (unsigned)(kk >> 32);
        nn = (unsigned)kk;
        sb0 = bb; sn0 = nn;
        DPP_LEXMAX_STEP(bb, nn, 0x111);
        DPP_LEXMAX_STEP(bb, nn, 0x112);
        DPP_LEXMAX_STEP(bb, nn, 0x114);
        DPP_LEXMAX_STEP(bb, nn, 0x118);
      }
      rb = (unsigned)rdlane((int)bb, 15);
      rn = (unsigned)rdlane((int)nn, 15);
    }
    unsigned long long wm = __ballot(lane < 16 && sb0 == rb && sn0 == rn);
    int ws = (int)__ffsll(wm) - 1;   // winning slot (wave) id — unique key
    float4 wp = spos[par][ws];       // single b128 broadcast read
    if (tid == 0) winners[m] = (int)(~rn);

    // prune: lower-bound distance from winner to chunk bbox
    float ex = fmaxf(fmaxf(bxm - wp.x, wp.x - bxM), 0.0f);
    float ey = fmaxf(fmaxf(bym - wp.y, wp.y - byM), 0.0f);
    float ez = fmaxf(fmaxf(bzm - wp.z, wp.z - bzM), 0.0f);
    float lb = (ex * ex + ey * ey + ez * ez) * 0.999f;
    bool mydirty = lb < __uint_as_float(tb);
    if (mydirty) {
      unsigned nb = 0u, nn2 = 0u;
      float nx = 0.f, ny = 0.f, nz = 0.f;
#pragma unroll
      for (int j = 0; j < 16; ++j) {
        float dj = fminf(d[j], d2e(px[j], py[j], pz[j], wp.x, wp.y, wp.z));
        d[j] = dj;
        unsigned db = __float_as_uint(dj);
        unsigned nj = nidx[j];
        bool t = (db > nb) || (db == nb && nj > nn2);
        nb = t ? db : nb; nn2 = t ? nj : nn2;
        nx = t ? px[j] : nx; ny = t ? py[j] : ny; nz = t ? pz[j] : nz;
      }
      tb = nb; tn = nn2; tx = nx; ty = ny; tz = nz;
    }
    wavedirty = (__ballot(mydirty) != 0ULL);
  }

  __syncthreads();
  for (int i = tid; i < MCENT; i += 1024) fps_idx[b * MCENT + i] = winners[i];
}

// ------------- Kernel 2: ball query + K-smallest selection (1 wave/centroid) --
__global__ __launch_bounds__(256) void ballq_kernel(const float* __restrict__ pos,
                                                    const int* __restrict__ fps_idx,
                                                    int* __restrict__ nbr,
                                                    float* __restrict__ out_pc,
                                                    float* __restrict__ out_batch) {
  const int wave = threadIdx.x >> 6;
  const int lane = threadIdx.x & 63;
  const int c = blockIdx.x * 4 + wave;   // global centroid id
  const int b = c >> 12;                 // 4096 centroids per cloud
  const float* P = pos + (size_t)b * NPTS * 3;

  const int ci = fps_idx[c];
  const float cx = P[3 * ci + 0];
  const float cy = P[3 * ci + 1];
  const float cz = P[3 * ci + 2];
  if (lane == 0) {
    out_pc[3 * c + 0] = cx;
    out_pc[3 * c + 1] = cy;
    out_pc[3 * c + 2] = cz;
    out_batch[c] = (float)b;
  }

  __shared__ unsigned long long list[4][1024];
  __shared__ int cnt[4];
  if (lane == 0) cnt[wave] = 0;

  for (int i = lane; i < NPTS; i += 64) {
    const float qx = P[3 * i + 0];
    const float qy = P[3 * i + 1];
    const float qz = P[3 * i + 2];
    const float dd = d2e(cx, cy, cz, qx, qy, qz);
    if (dd <= R2CUT) {
      int p = atomicAdd(&cnt[wave], 1);
      if (p < 1024)
        list[wave][p] = ((unsigned long long)__float_as_uint(dd) << 32)
                      | (unsigned long long)(unsigned)i;
    }
  }
  __syncthreads();

  int n = cnt[wave];
  if (n > 1024) n = 1024;

  unsigned long long loc[16];
#pragma unroll
  for (int k = 0; k < 16; ++k) {
    int i = lane + k * 64;
    loc[k] = (i < n) ? list[wave][i] : ~0ULL;
  }
  unsigned long long mv = loc[0];
#pragma unroll
  for (int k = 1; k < 16; ++k)
    if (loc[k] < mv) mv = loc[k];

  int myout = -1;
  for (int s = 0; s < 64; ++s) {
    unsigned long long wmin = mv;
#pragma unroll
    for (int off = 32; off >= 1; off >>= 1) {
      unsigned long long o = __shfl_xor(wmin, off);
      if (o < wmin) wmin = o;
    }
    if (lane == s) myout = (wmin == ~0ULL) ? -1 : (int)(unsigned)wmin;
    if (mv == wmin && wmin != ~0ULL) {
#pragma unroll
      for (int k = 0; k < 16; ++k)
        if (loc[k] == wmin) loc[k] = ~0ULL;
      mv = loc[0];
#pragma unroll
      for (int k = 1; k < 16; ++k)
        if (loc[k] < mv) mv = loc[k];
    }
  }
  nbr[c * KNBR + lane] = myout;
}

// ------------- Kernel 3: MLP (35->64 relu ->128) + masked max-pool ----------
__global__ __launch_bounds__(256) void mlp_kernel(const float* __restrict__ pos,
                                                  const float* __restrict__ x,
                                                  const int* __restrict__ fps_idx,
                                                  const int* __restrict__ nbr,
                                                  const float* __restrict__ W1,
                                                  const float* __restrict__ b1,
                                                  const float* __restrict__ W2,
                                                  const float* __restrict__ b2,
                                                  float* __restrict__ out) {
  const int c = blockIdx.x;
  const int b = c >> 12;
  const float* P = pos + (size_t)b * NPTS * 3;
  const float* X = x + (size_t)b * NPTS * FDIM;

  __shared__ float W1s[35 * 64];
  __shared__ float W2s[64 * 128];
  __shared__ float b1s[64];
  __shared__ float b2s[128];
  __shared__ float h1s[64][64];
  __shared__ float pmax[2][128];
  __shared__ int validk[64];

  const int tid = threadIdx.x;
  for (int i = tid; i < 35 * 64; i += 256) W1s[i] = W1[i];
  for (int i = tid; i < 64 * 128; i += 256) W2s[i] = W2[i];
  if (tid < 64) b1s[tid] = b1[tid];
  else if (tid < 192) b2s[tid - 64] = b2[tid - 64];

  const int ci = fps_idx[c];
  const float c5x = P[3 * ci + 0] / 0.2f;  // faithful: pos_i / r
  const float c5y = P[3 * ci + 1] / 0.2f;
  const float c5z = P[3 * ci + 2] / 0.2f;

  const int k = tid >> 2, q = tid & 3;
  const int nk = nbr[c * KNBR + k];
  if (q == 0) validk[k] = (nk >= 0) ? 1 : 0;
  const int nkc = (nk < 0) ? 0 : nk;

  float msg[35];
  const float4* Xr = (const float4*)(X + (size_t)nkc * FDIM);
#pragma unroll
  for (int i4 = 0; i4 < 8; ++i4) {
    float4 v = Xr[i4];
    msg[i4 * 4 + 0] = v.x; msg[i4 * 4 + 1] = v.y;
    msg[i4 * 4 + 2] = v.z; msg[i4 * 4 + 3] = v.w;
  }
  msg[32] = P[3 * nkc + 0] - c5x;
  msg[33] = P[3 * nkc + 1] - c5y;
  msg[34] = P[3 * nkc + 2] - c5z;

  __syncthreads();

  float acc[16];
#pragma unroll
  for (int h = 0; h < 16; ++h) acc[h] = b1s[q * 16 + h];
#pragma unroll
  for (int i = 0; i < 35; ++i) {
    const float m = msg[i];
    const float4* wrow = (const float4*)&W1s[i * 64 + q * 16];
#pragma unroll
    for (int j4 = 0; j4 < 4; ++j4) {
      float4 w = wrow[j4];
      acc[j4 * 4 + 0] += m * w.x;
      acc[j4 * 4 + 1] += m * w.y;
      acc[j4 * 4 + 2] += m * w.z;
      acc[j4 * 4 + 3] += m * w.w;
    }
  }
#pragma unroll
  for (int h = 0; h < 16; ++h) h1s[k][q * 16 + h] = fmaxf(acc[h], 0.0f);
  __syncthreads();

  const int ch = tid & 127, half = tid >> 7;
  float w2r[64];
#pragma unroll
  for (int i = 0; i < 64; ++i) w2r[i] = W2s[i * 128 + ch];

  float mx = -INFINITY;
  for (int k2 = half * 32; k2 < half * 32 + 32; ++k2) {
    if (!validk[k2]) continue;
    float s = b2s[ch];
    const float4* hr = (const float4*)h1s[k2];
#pragma unroll
    for (int i4 = 0; i4 < 16; ++i4) {
      float4 h4 = hr[i4];
      s += h4.x * w2r[i4 * 4 + 0] + h4.y * w2r[i4 * 4 + 1]
         + h4.z * w2r[i4 * 4 + 2] + h4.w * w2r[i4 * 4 + 3];
    }
    mx = fmaxf(mx, s);
  }
  pmax[half][ch] = mx;
  __syncthreads();

  if (tid < 128) {
    float m2 = fmaxf(pmax[0][tid], pmax[1][tid]);
    out[(size_t)c * CODIM + tid] = (m2 > -INFINITY) ? m2 : 0.0f;
  }
}

extern "C" void kernel_launch(void* const* d_in, const int* in_sizes, int n_in,
                              void* d_out, int out_size, void* d_ws, size_t ws_size,
                              hipStream_t stream) {
  const float* x   = (const float*)d_in[0];
  const float* pos = (const float*)d_in[1];
  const float* W1  = (const float*)d_in[3];
  const float* b1  = (const float*)d_in[4];
  const float* W2  = (const float*)d_in[5];
  const float* b2  = (const float*)d_in[6];
  float* out = (float*)d_out;

  int* fps_idx = (int*)d_ws;                  // B*M ints = 32 KiB
  int* nbr     = (int*)d_ws + BCLD * MCENT;   // B*M*K ints = 2 MiB
  // fps scratch aliases the nbr region (fps completes before ballq writes nbr)
  float4* ws_sorted = (float4*)nbr;           // B*N float4 = 512 KiB

  float* out_pc    = out + (size_t)BCLD * MCENT * CODIM;
  float* out_batch = out_pc + (size_t)BCLD * MCENT * 3;

  hipLaunchKernelGGL(fps_kernel, dim3(BCLD), dim3(1024), 0, stream, pos, fps_idx, ws_sorted);
  hipLaunchKernelGGL(ballq_kernel, dim3(BCLD * MCENT / 4), dim3(256), 0, stream,
                     pos, fps_idx, nbr, out_pc, out_batch);
  hipLaunchKernelGGL(mlp_kernel, dim3(BCLD * MCENT), dim3(256), 0, stream,
                     pos, x, fps_idx, nbr, W1, b1, W2, b2, out);
}